// Round 9
// baseline (165.093 us; speedup 1.0000x reference)
//
#include <hip/hip_runtime.h>
#include <math.h>

#define N_NODES 20000
#define N_EDGES 320000
#define NG 64
#define NEG 0.2f
#define NCHUNK ((N_NODES + 255) / 256)   // 79
#define FLAGBIT (1 << 30)

typedef __attribute__((ext_vector_type(8))) short bf16x8;
typedef __attribute__((ext_vector_type(4))) float f32x4;

__device__ __forceinline__ unsigned short f2bf(float f) {
  unsigned int u = __float_as_uint(f);
  return (unsigned short)((u + 0x7fffu + ((u >> 16) & 1u)) >> 16);
}

// ---------------------------------------------------------------------------
// k_prep (one kernel, index ranges):
//  [0,1280)        wsall[20][64]: folded alpha weights (set, role, head)
//  [..+49152)      wbigfrag: bf16 MFMA B-fragments of Wbig[768][64]
//  block 197       bfold[64] = bf + concat(b_i,b_t) @ Wf (cooperative)
//  then            zero fill_i / fill_t / gsum / gcnt / aggs
// ---------------------------------------------------------------------------
__global__ __launch_bounds__(256) void k_prep(
    const float* __restrict__ W_i, const float* __restrict__ as_i, const float* __restrict__ ad_i,
    const float* __restrict__ W_t, const float* __restrict__ as_t, const float* __restrict__ ad_t,
    const float* __restrict__ Wf, const float* __restrict__ bf,
    const float* __restrict__ b_i, const float* __restrict__ b_t,
    float* __restrict__ wsall, unsigned short* __restrict__ wbigfrag,
    float* __restrict__ bfold,
    int* __restrict__ fill_i, int* __restrict__ fill_t,
    float* __restrict__ gsum, int* __restrict__ gcnt, int* __restrict__ aggs) {
  __shared__ float bred[4][64];
  int idx = blockIdx.x * 256 + threadIdx.x;
  if (idx < 1280) {
    int k = idx >> 6, c = idx & 63;
    int set = c >> 5, role = (c >> 4) & 1, h = c & 15;
    const float* W = set ? W_t : W_i;
    const float* a = set ? (role ? ad_t : as_t) : (role ? ad_i : as_i);
    float v = 0.f;
#pragma unroll
    for (int j = 0; j < 16; ++j) v = fmaf(W[k * 256 + h * 16 + j], a[h * 16 + j], v);
    wsall[idx] = v;
    return;
  }
  idx -= 1280;
  if (idx < 49152) {
    int ct = idx / 12288, rem = idx % 12288;
    int lane = (rem >> 3) & 63, j = rem & 7, ks = rem >> 9;
    int k = ks * 32 + ((lane >> 4) << 3) + j;
    int nc = ct * 16 + (lane & 15);
    float v = 0.f;
    int g = (k >= 384) ? 1 : 0;
    int r = k - g * 384;
    int h = r / 24, c = r - h * 24;
    if (c < 20) {
      const float* W = g ? W_t : W_i;
      const float* wr = W + c * 256 + (h << 4);
      const float* wf = Wf + ((g << 8) + (h << 4)) * 64 + nc;
#pragma unroll
      for (int m = 0; m < 16; ++m) v = fmaf(wr[m], wf[m * 64], v);
    }
    wbigfrag[idx] = f2bf(v);
    return;
  }
  idx -= 49152;
  if (idx < 256) {
    int t = threadIdx.x, wv = t >> 6, j = t & 63;
    float p = 0.f;
    int i0 = wv * 128;
#pragma unroll 4
    for (int i = i0; i < i0 + 128; ++i) {
      float b = (i < 256) ? b_i[i] : b_t[i - 256];
      p = fmaf(b, Wf[i * 64 + j], p);
    }
    bred[wv][j] = p;
    __syncthreads();
    if (wv == 0) bfold[j] = bred[0][j] + bred[1][j] + bred[2][j] + bred[3][j] + bf[j];
    return;
  }
  idx -= 256;
  if (idx < N_NODES) { fill_i[idx] = 0; return; }
  idx -= N_NODES;
  if (idx < N_NODES) { fill_t[idx] = 0; return; }
  idx -= N_NODES;
  if (idx < NG * 16) { gsum[idx] = 0.f; return; }
  idx -= NG * 16;
  if (idx < NG) { gcnt[idx] = 0; return; }
  idx -= NG;
  if (idx < 256) aggs[idx] = 0;
}

// ---------------------------------------------------------------------------
// k_alpha: 16 nodes/block. asrc/adst (both sets) = x @ wsall; writes xpad.
// ---------------------------------------------------------------------------
__global__ __launch_bounds__(256) void k_alpha(
    const float* __restrict__ x, const float* __restrict__ wsall,
    float* __restrict__ xpad,
    float* __restrict__ asrc0, float* __restrict__ adst0,
    float* __restrict__ asrc1, float* __restrict__ adst1) {
  int t = threadIdx.x;
  int n0 = blockIdx.x * 16;
  __shared__ float xs[16][20];
  __shared__ float ws[20][64];
  for (int i = t; i < 16 * 20; i += 256) {
    int nd = i / 20, k = i % 20;
    xs[nd][k] = x[(n0 + nd) * 20 + k];
  }
  for (int i = t; i < 1280; i += 256) ws[i >> 6][i & 63] = wsall[i];
  __syncthreads();
  for (int i = t; i < 512; i += 256) {
    int nd = i >> 5, j = i & 31;
    xpad[(size_t)(n0 + nd) * 32 + j] = (j < 20) ? xs[nd][j] : 0.f;
  }
#pragma unroll
  for (int i = 0; i < 4; ++i) {
    int wi = i * 256 + t;
    int nd = wi >> 6, c = wi & 63;
    float v = 0.f;
#pragma unroll
    for (int k = 0; k < 20; ++k) v = fmaf(xs[nd][k], ws[k][c], v);
    int n = n0 + nd, h = c & 15;
    float* arr = (c >> 5) ? ((c >> 4) & 1 ? adst1 : asrc1)
                          : ((c >> 4) & 1 ? adst0 : asrc0);
    arr[n * 16 + h] = v;
  }
}

// ---------------------------------------------------------------------------
// CSR build
// ---------------------------------------------------------------------------
__global__ void k_hist(const int* __restrict__ ei0, const int* __restrict__ ei1,
                       int* __restrict__ cnt0, int* __restrict__ cnt1) {
  int e = blockIdx.x * blockDim.x + threadIdx.x;
  if (e >= N_EDGES) return;
  if (blockIdx.y == 0)
    atomicAdd(&cnt0[ei0[N_EDGES + e]], 1);
  else
    atomicAdd(&cnt1[ei1[N_EDGES + e]], 1);
}

// fused decoupled-lookback scan (proven in R7). Grid (79,2), all co-resident.
__global__ __launch_bounds__(256) void k_scan(
    int* __restrict__ fill0, int* __restrict__ fill1,
    int* __restrict__ rp0, int* __restrict__ rp1,
    int* __restrict__ aggs) {
  int chunk = blockIdx.x, set = blockIdx.y;
  int* fill = set ? fill1 : fill0;
  int* rp = set ? rp1 : rp0;
  int t = threadIdx.x, lane = t & 63, wv = t >> 6;
  int i = chunk * 256 + t;
  int v = (i < N_NODES) ? fill[i] : 0;
  int s = v;
#pragma unroll
  for (int d = 1; d < 64; d <<= 1) {
    int o = __shfl_up(s, d);
    if (lane >= d) s += o;
  }
  __shared__ int wsum[4];
  if (lane == 63) wsum[wv] = s;
  __syncthreads();
  int pre = 0;
#pragma unroll
  for (int j = 0; j < 4; ++j)
    if (j < wv) pre += wsum[j];
  s += pre;
  int agg = wsum[0] + wsum[1] + wsum[2] + wsum[3];
  if (t == 0)
    __hip_atomic_store(&aggs[set * 128 + chunk], agg | FLAGBIT,
                       __ATOMIC_RELEASE, __HIP_MEMORY_SCOPE_AGENT);
  __shared__ int reds[256];
  int part = 0;
  for (int j = t; j < chunk; j += 256) {
    int a;
    do {
      a = __hip_atomic_load(&aggs[set * 128 + j], __ATOMIC_ACQUIRE,
                            __HIP_MEMORY_SCOPE_AGENT);
    } while (!(a & FLAGBIT));
    part += a & (FLAGBIT - 1);
  }
  reds[t] = part;
  __syncthreads();
  for (int st = 128; st > 0; st >>= 1) {
    if (t < st) reds[t] += reds[t + st];
    __syncthreads();
  }
  int carry = reds[0];
  int excl = carry + s - v;
  if (i < N_NODES) {
    rp[i] = excl;
    fill[i] = excl;
    if (i == N_NODES - 1) rp[N_NODES] = excl + v;
  }
}

__global__ void k_scatter(const int* __restrict__ ei0, const int* __restrict__ ei1,
                          int* __restrict__ fill0, int* __restrict__ fill1,
                          unsigned short* __restrict__ srcs0,
                          unsigned short* __restrict__ srcs1) {
  int e = blockIdx.x * blockDim.x + threadIdx.x;
  if (e >= N_EDGES) return;
  const int* ei = blockIdx.y ? ei1 : ei0;
  int* fill = blockIdx.y ? fill1 : fill0;
  unsigned short* srcs = blockIdx.y ? srcs1 : srcs0;
  int d = ei[N_EDGES + e];
  int pos = atomicAdd(&fill[d], 1);
  srcs[pos] = (unsigned short)ei[e];
}

// ---------------------------------------------------------------------------
// k_gat: ONE WAVE PER (node, set), 16-edge batches, 2-level pipeline
// (srcs 2 batches ahead, xpad+asrc data 1 ahead). Lane (eid,slot) loads:
// 2 float4 of xpad row + 1 float4 of asrc (4 heads of its edge) -> 4 exps
// from registers (no shfl, no scalar gathers) -> LDS la[16][16] + xs[16][36].
// Accumulate lane (h16,e4): 16 x (b32 + 2 b128 + 8 FMA); denom summed free
// in the same loop (no cross-lane reduce). Writes xagg bf16 [N][768].
// ---------------------------------------------------------------------------
__global__ __launch_bounds__(256) void k_gat(
    const float* __restrict__ xpad,
    const float* __restrict__ asrc0, const float* __restrict__ adst0,
    const float* __restrict__ asrc1, const float* __restrict__ adst1,
    const int* __restrict__ rp0, const unsigned short* __restrict__ srcs0,
    const int* __restrict__ rp1, const unsigned short* __restrict__ srcs1,
    unsigned short* __restrict__ xagg) {
  __shared__ float xsh[4][16][36];
  __shared__ float lath[4][16][16];
  int w4 = threadIdx.x >> 6, lane = threadIdx.x & 63;
  int n = blockIdx.x * 2 + (w4 >> 1);
  int g = w4 & 1;
  int h16 = lane & 15, e4 = lane >> 4;    // accumulate roles
  int eid = lane & 15, slot = lane >> 4;  // load/exp roles
  float (*xs)[36] = xsh[w4];
  float (*la)[16] = lath[w4];
  const float* asrc = g ? asrc1 : asrc0;
  const float* adst = g ? adst1 : adst0;
  const int* rp = g ? rp1 : rp0;
  const unsigned short* srcs = g ? srcs1 : srcs0;
  int k0 = rp[n], k1 = rp[n + 1];
  float4 adn4 = *(const float4*)&adst[n * 16 + slot * 4];
  float lacc = 0.f;
  float xa[8];
#pragma unroll
  for (int j = 0; j < 8; ++j) xa[j] = 0.f;
  if (k1 > k0) {
    int nbat = (k1 - k0 + 15) >> 4;
    // prologue: batch 0 data, batch 1 srcs
    int sb = (int)srcs[min(k0 + eid, k1 - 1)];
    float4 xv0 = *(const float4*)&xpad[(size_t)sb * 32 + slot * 8];
    float4 xv1 = *(const float4*)&xpad[(size_t)sb * 32 + slot * 8 + 4];
    float4 av4 = *(const float4*)&asrc[(size_t)sb * 16 + slot * 4];
    int sbN = 0;
    if (nbat > 1) sbN = (int)srcs[min(k0 + 16 + eid, k1 - 1)];
    for (int bb = 0; bb < nbat; ++bb) {
      // prefetch: batch bb+1 data, batch bb+2 srcs
      float4 xv0N = {0.f,0.f,0.f,0.f}, xv1N = xv0N, av4N = xv0N;
      int sbNN = 0;
      if (bb + 1 < nbat) {
        xv0N = *(const float4*)&xpad[(size_t)sbN * 32 + slot * 8];
        xv1N = *(const float4*)&xpad[(size_t)sbN * 32 + slot * 8 + 4];
        av4N = *(const float4*)&asrc[(size_t)sbN * 16 + slot * 4];
      }
      if (bb + 2 < nbat)
        sbNN = (int)srcs[min(k0 + (bb + 2) * 16 + eid, k1 - 1)];
      // exps for this lane's edge (4 heads), zero if edge invalid
      bool val = (k0 + bb * 16 + eid) < k1;
      float4 ex4;
      {
        float a;
        a = av4.x + adn4.x; a = a >= 0.f ? a : NEG * a; ex4.x = val ? __expf(a) : 0.f;
        a = av4.y + adn4.y; a = a >= 0.f ? a : NEG * a; ex4.y = val ? __expf(a) : 0.f;
        a = av4.z + adn4.z; a = a >= 0.f ? a : NEG * a; ex4.z = val ? __expf(a) : 0.f;
        a = av4.w + adn4.w; a = a >= 0.f ? a : NEG * a; ex4.w = val ? __expf(a) : 0.f;
      }
      // stage (wave-synchronous LDS)
      *(float4*)&xs[eid][slot * 8] = xv0;
      *(float4*)&xs[eid][slot * 8 + 4] = xv1;
      *(float4*)&la[eid][slot * 4] = ex4;
      // accumulate 16 edges; denom summed inline (same for all e4 lanes)
#pragma unroll
      for (int e = 0; e < 16; ++e) {
        float w = la[e][h16];
        lacc += w;
        float4 x0 = *(const float4*)&xs[e][e4 * 8];
        float4 x1 = *(const float4*)&xs[e][e4 * 8 + 4];
        xa[0] = fmaf(w, x0.x, xa[0]); xa[1] = fmaf(w, x0.y, xa[1]);
        xa[2] = fmaf(w, x0.z, xa[2]); xa[3] = fmaf(w, x0.w, xa[3]);
        xa[4] = fmaf(w, x1.x, xa[4]); xa[5] = fmaf(w, x1.y, xa[5]);
        xa[6] = fmaf(w, x1.z, xa[6]); xa[7] = fmaf(w, x1.w, xa[7]);
      }
      xv0 = xv0N; xv1 = xv1N; av4 = av4N; sb = sbN; sbN = sbNN;
    }
  }
  float invl = lacc > 0.f ? 1.f / lacc : 0.f;
  if (e4 < 3) {
    unsigned int u[4];
#pragma unroll
    for (int q = 0; q < 4; ++q)
      u[q] = (unsigned int)f2bf(xa[2 * q] * invl) |
             ((unsigned int)f2bf(xa[2 * q + 1] * invl) << 16);
    *(uint4*)&xagg[(size_t)n * 768 + g * 384 + h16 * 24 + e4 * 8] = *(uint4*)u;
  }
}

// ---------------------------------------------------------------------------
// k_mlp: 16 nodes/block (1250 blocks). Wave w computes one col-tile of
// layer 1 via 24-step bf16 MFMA; layers 2-4 (node,col) threads; pool.
// ---------------------------------------------------------------------------
__global__ __launch_bounds__(256) void k_mlp(
    const unsigned short* __restrict__ xagg, const unsigned short* __restrict__ wbigfrag,
    const float* __restrict__ bfold,
    const float* __restrict__ W1m, const float* __restrict__ b1v,
    const float* __restrict__ W2m, const float* __restrict__ b2v,
    const float* __restrict__ W3m, const float* __restrict__ b3v,
    const int* __restrict__ batch,
    float* __restrict__ gsum, int* __restrict__ gcnt) {
  int t = threadIdx.x, w = t >> 6, lane = t & 63;
  int n0 = blockIdx.x * 16;
  __shared__ float o1[16][68];
  __shared__ float o2[16][36];
  __shared__ float o3[16][20];
  __shared__ float o4[16][17];
  __shared__ int bs[16];
  if (t < 16) bs[t] = batch[n0 + t];

  {
    int m = lane & 15, kb = lane >> 4;
    const unsigned short* aptr = xagg + (size_t)(n0 + m) * 768 + kb * 8;
    const unsigned short* bbase = wbigfrag + (size_t)w * 12288 + lane * 8;
    f32x4 acc = {0.f, 0.f, 0.f, 0.f};
#pragma unroll 6
    for (int ks = 0; ks < 24; ++ks) {
      bf16x8 af = *(const bf16x8*)(aptr + ks * 32);
      bf16x8 bfr = *(const bf16x8*)(bbase + (size_t)ks * 512);
      acc = __builtin_amdgcn_mfma_f32_16x16x32_bf16(af, bfr, acc, 0, 0, 0);
    }
    int col = lane & 15, rg = lane >> 4;
#pragma unroll
    for (int r = 0; r < 4; ++r) {
      int row = rg * 4 + r;
      o1[row][w * 16 + col] = fmaxf(acc[r] + bfold[w * 16 + col], 0.f);
    }
  }
  __syncthreads();
  int nd = t >> 4, js = t & 15;
  {
    float a0 = b1v[js], a1 = b1v[js + 16];
#pragma unroll 8
    for (int k = 0; k < 64; ++k) {
      float hv = o1[nd][k];
      a0 = fmaf(hv, W1m[k * 32 + js], a0);
      a1 = fmaf(hv, W1m[k * 32 + js + 16], a1);
    }
    o2[nd][js] = fmaxf(a0, 0.f);
    o2[nd][js + 16] = fmaxf(a1, 0.f);
  }
  __syncthreads();
  {
    float a = b2v[js];
#pragma unroll
    for (int k = 0; k < 32; ++k) a = fmaf(o2[nd][k], W2m[k * 16 + js], a);
    o3[nd][js] = fmaxf(a, 0.f);
  }
  __syncthreads();
  {
    float a = b3v[js];
#pragma unroll
    for (int k = 0; k < 16; ++k) a = fmaf(o3[nd][k], W3m[k * 16 + js], a);
    o4[nd][js] = fmaxf(a, 0.f);
  }
  __syncthreads();
  if (t < 128) {
    int s = t >> 4, jx = t & 15;
    int b = bs[0] + s;
    if (b <= bs[15]) {
      float sum = 0.f; int c = 0;
#pragma unroll
      for (int ndd = 0; ndd < 16; ++ndd)
        if (bs[ndd] == b) { sum += o4[ndd][jx]; ++c; }
      if (c > 0) {
        atomicAdd(&gsum[b * 16 + jx], sum);
        if (jx == 0) atomicAdd(&gcnt[b], c);
      }
    }
  }
}

__global__ void k_head(const float* __restrict__ gsum, const int* __restrict__ gcnt,
                       const float* __restrict__ Wce, const float* __restrict__ bce,
                       const float* __restrict__ Wcv, const float* __restrict__ bcv,
                       float* __restrict__ out) {
  int t = threadIdx.x;
  if (t >= 384) return;
  int half = t / 192, idx = t % 192;
  int b = idx / 3, r = idx % 3;
  float cnt = (float)gcnt[b];
  float inv = cnt > 0.f ? 1.f / cnt : 1.f;
  const float* Wc = half ? Wcv : Wce;
  const float* bc = half ? bcv : bce;
  float v = bc[r];
#pragma unroll
  for (int j = 0; j < 16; ++j) v = fmaf(gsum[b * 16 + j] * inv, Wc[j * 3 + r], v);
  out[t] = v;
}

extern "C" void kernel_launch(void* const* d_in, const int* in_sizes, int n_in,
                              void* d_out, int out_size, void* d_ws, size_t ws_size,
                              hipStream_t stream) {
  const float* x = (const float*)d_in[0];
  const int* ei_i = (const int*)d_in[1];
  const int* ei_t = (const int*)d_in[3];
  const int* batch = (const int*)d_in[5];
  const float* W_i = (const float*)d_in[6];
  const float* as_i = (const float*)d_in[7];
  const float* ad_i = (const float*)d_in[8];
  const float* b_i = (const float*)d_in[9];
  const float* W_t = (const float*)d_in[10];
  const float* as_t = (const float*)d_in[11];
  const float* ad_t = (const float*)d_in[12];
  const float* b_t = (const float*)d_in[13];
  const float* Wf = (const float*)d_in[14];
  const float* bf = (const float*)d_in[15];
  const float* W1 = (const float*)d_in[16];
  const float* b1 = (const float*)d_in[17];
  const float* W2 = (const float*)d_in[18];
  const float* b2 = (const float*)d_in[19];
  const float* W3 = (const float*)d_in[20];
  const float* b3 = (const float*)d_in[21];
  const float* Wce = (const float*)d_in[22];
  const float* bce = (const float*)d_in[23];
  const float* Wcv = (const float*)d_in[24];
  const float* bcv = (const float*)d_in[25];

  char* ws = (char*)d_ws;
  size_t off = 0;
  auto take = [&](size_t bytes) {
    void* p = ws + off;
    off = (off + bytes + 255) & ~(size_t)255;
    return p;
  };
  float* xpad = (float*)take((size_t)N_NODES * 32 * 4);
  unsigned short* xagg = (unsigned short*)take((size_t)N_NODES * 768 * 2);
  float* wsall = (float*)take((size_t)1280 * 4);
  unsigned short* wbigfrag = (unsigned short*)take((size_t)49152 * 2);
  float* bfold = (float*)take((size_t)64 * 4);
  float* asrc_i = (float*)take((size_t)N_NODES * 16 * 4);
  float* adst_i = (float*)take((size_t)N_NODES * 16 * 4);
  float* asrc_t = (float*)take((size_t)N_NODES * 16 * 4);
  float* adst_t = (float*)take((size_t)N_NODES * 16 * 4);
  int* rowptr_i = (int*)take((size_t)(N_NODES + 1) * 4);
  int* rowptr_t = (int*)take((size_t)(N_NODES + 1) * 4);
  int* fill_i = (int*)take((size_t)N_NODES * 4);
  int* fill_t = (int*)take((size_t)N_NODES * 4);
  int* csums = (int*)take((size_t)2 * 128 * 4);
  unsigned short* srcs_i = (unsigned short*)take((size_t)N_EDGES * 2);
  unsigned short* srcs_t = (unsigned short*)take((size_t)N_EDGES * 2);
  float* gsum = (float*)take((size_t)NG * 16 * 4);
  int* gcnt = (int*)take((size_t)NG * 4);

  int prep_items = 1280 + 49152 + 256 + N_NODES + N_NODES + NG * 16 + NG + 256;
  k_prep<<<(prep_items + 255) / 256, 256, 0, stream>>>(
      W_i, as_i, ad_i, W_t, as_t, ad_t, Wf, bf, b_i, b_t,
      wsall, wbigfrag, bfold, fill_i, fill_t, gsum, gcnt, csums);

  k_alpha<<<N_NODES / 16, 256, 0, stream>>>(x, wsall, xpad,
                                            asrc_i, adst_i, asrc_t, adst_t);

  dim3 egrid((N_EDGES + 255) / 256, 2);
  k_hist<<<egrid, 256, 0, stream>>>(ei_i, ei_t, fill_i, fill_t);
  dim3 sgrid(NCHUNK, 2);
  k_scan<<<sgrid, 256, 0, stream>>>(fill_i, fill_t, rowptr_i, rowptr_t, csums);
  k_scatter<<<egrid, 256, 0, stream>>>(ei_i, ei_t, fill_i, fill_t, srcs_i, srcs_t);

  k_gat<<<N_NODES / 2, 256, 0, stream>>>(xpad, asrc_i, adst_i, asrc_t, adst_t,
                                         rowptr_i, srcs_i, rowptr_t, srcs_t,
                                         xagg);

  k_mlp<<<N_NODES / 16, 256, 0, stream>>>(xagg, wbigfrag, bfold,
                                          W1, b1, W2, b2, W3, b3,
                                          batch, gsum, gcnt);

  k_head<<<1, 384, 0, stream>>>(gsum, gcnt, Wce, bce, Wcv, bcv, (float*)d_out);
}

// Round 10
// 136.810 us; speedup vs baseline: 1.2067x; 1.2067x over previous
//
#include <hip/hip_runtime.h>
#include <math.h>

#define N_NODES 20000
#define N_EDGES 320000
#define NG 64
#define NEG 0.2f
#define NCHUNK ((N_NODES + 255) / 256)   // 79
#define FLAGBIT (1 << 30)

typedef __attribute__((ext_vector_type(8))) short bf16x8;
typedef __attribute__((ext_vector_type(4))) float f32x4;

__device__ __forceinline__ unsigned short f2bf(float f) {
  unsigned int u = __float_as_uint(f);
  return (unsigned short)((u + 0x7fffu + ((u >> 16) & 1u)) >> 16);
}
__device__ __forceinline__ unsigned int pk2bf(float a, float b) {
  return (unsigned int)f2bf(a) | ((unsigned int)f2bf(b) << 16);
}

// ---------------------------------------------------------------------------
// k_prep (index ranges):
//  [0,1280)    wsall[20][64]: folded alpha weights
//  [..+40960)  wbigfrag: bf16 MFMA B-frags of Wbig[640][64];
//              row k = g*320 + ch*16 + h (ch<20 real, ch>=20 zero):
//              Wbig[k][j] = sum_m W_g[ch][h*16+m] * Wf[(g*256+h*16+m)][j]
//  [..+256)    block: cooperative bfold[64] = bf + concat(b_i,b_t)@Wf
//  then        zero fill_i / fill_t / gsum / gcnt / aggs
// ---------------------------------------------------------------------------
__global__ __launch_bounds__(256) void k_prep(
    const float* __restrict__ W_i, const float* __restrict__ as_i, const float* __restrict__ ad_i,
    const float* __restrict__ W_t, const float* __restrict__ as_t, const float* __restrict__ ad_t,
    const float* __restrict__ Wf, const float* __restrict__ bf,
    const float* __restrict__ b_i, const float* __restrict__ b_t,
    float* __restrict__ wsall, unsigned short* __restrict__ wbigfrag,
    float* __restrict__ bfold,
    int* __restrict__ fill_i, int* __restrict__ fill_t,
    float* __restrict__ gsum, int* __restrict__ gcnt, int* __restrict__ aggs) {
  __shared__ float bred[4][64];
  int idx = blockIdx.x * 256 + threadIdx.x;
  if (idx < 1280) {
    int k = idx >> 6, c = idx & 63;
    int set = c >> 5, role = (c >> 4) & 1, h = c & 15;
    const float* W = set ? W_t : W_i;
    const float* a = set ? (role ? ad_t : as_t) : (role ? ad_i : as_i);
    float v = 0.f;
#pragma unroll
    for (int j = 0; j < 16; ++j) v = fmaf(W[k * 256 + h * 16 + j], a[h * 16 + j], v);
    wsall[idx] = v;
    return;
  }
  idx -= 1280;
  if (idx < 40960) {
    int ct = idx / 10240, rem = idx % 10240;
    int lane = (rem >> 3) & 63, j = rem & 7, ks = rem >> 9;  // ks 0..19
    int k = ks * 32 + ((lane >> 4) << 3) + j;                // 0..639
    int nc = ct * 16 + (lane & 15);
    int g = (k >= 320) ? 1 : 0;
    int r = k - g * 320;
    int ch = r >> 4, h = r & 15;
    float v = 0.f;
    if (ch < 20) {
      const float* W = g ? W_t : W_i;
      const float* wr = W + ch * 256 + (h << 4);
      const float* wf = Wf + ((g << 8) + (h << 4)) * 64 + nc;
#pragma unroll
      for (int m = 0; m < 16; ++m) v = fmaf(wr[m], wf[m * 64], v);
    }
    wbigfrag[idx] = f2bf(v);
    return;
  }
  idx -= 40960;
  if (idx < 256) {
    int t = threadIdx.x, wv = t >> 6, j = t & 63;
    float p = 0.f;
    int i0 = wv * 128;
#pragma unroll 4
    for (int i = i0; i < i0 + 128; ++i) {
      float b = (i < 256) ? b_i[i] : b_t[i - 256];
      p = fmaf(b, Wf[i * 64 + j], p);
    }
    bred[wv][j] = p;
    __syncthreads();
    if (wv == 0) bfold[j] = bred[0][j] + bred[1][j] + bred[2][j] + bred[3][j] + bf[j];
    return;
  }
  idx -= 256;
  if (idx < N_NODES) { fill_i[idx] = 0; return; }
  idx -= N_NODES;
  if (idx < N_NODES) { fill_t[idx] = 0; return; }
  idx -= N_NODES;
  if (idx < NG * 16) { gsum[idx] = 0.f; return; }
  idx -= NG * 16;
  if (idx < NG) { gcnt[idx] = 0; return; }
  idx -= NG;
  if (idx < 256) aggs[idx] = 0;
}

// ---------------------------------------------------------------------------
// k_alpha: 16 nodes/block. asrc/adst = x @ wsall; writes xpadbf (bf16 [N][32],
// ch20 = 1.0 -> MFMA ones-column => free softmax denominator).
// ---------------------------------------------------------------------------
__global__ __launch_bounds__(256) void k_alpha(
    const float* __restrict__ x, const float* __restrict__ wsall,
    unsigned short* __restrict__ xpadbf,
    float* __restrict__ asrc0, float* __restrict__ adst0,
    float* __restrict__ asrc1, float* __restrict__ adst1) {
  int t = threadIdx.x;
  int n0 = blockIdx.x * 16;
  __shared__ float xs[16][20];
  __shared__ float ws[20][64];
  for (int i = t; i < 16 * 20; i += 256) {
    int nd = i / 20, k = i % 20;
    xs[nd][k] = x[(n0 + nd) * 20 + k];
  }
  for (int i = t; i < 1280; i += 256) ws[i >> 6][i & 63] = wsall[i];
  __syncthreads();
  for (int i = t; i < 512; i += 256) {
    int nd = i >> 5, j = i & 31;
    float v = (j < 20) ? xs[nd][j] : (j == 20 ? 1.f : 0.f);
    xpadbf[(size_t)(n0 + nd) * 32 + j] = f2bf(v);
  }
#pragma unroll
  for (int i = 0; i < 4; ++i) {
    int wi = i * 256 + t;
    int nd = wi >> 6, c = wi & 63;
    float v = 0.f;
#pragma unroll
    for (int k = 0; k < 20; ++k) v = fmaf(xs[nd][k], ws[k][c], v);
    int n = n0 + nd, h = c & 15;
    float* arr = (c >> 5) ? ((c >> 4) & 1 ? adst1 : asrc1)
                          : ((c >> 4) & 1 ? adst0 : asrc0);
    arr[n * 16 + h] = v;
  }
}

// ---------------------------------------------------------------------------
// CSR build
// ---------------------------------------------------------------------------
__global__ void k_hist(const int* __restrict__ ei0, const int* __restrict__ ei1,
                       int* __restrict__ cnt0, int* __restrict__ cnt1) {
  int e = blockIdx.x * blockDim.x + threadIdx.x;
  if (e >= N_EDGES) return;
  if (blockIdx.y == 0)
    atomicAdd(&cnt0[ei0[N_EDGES + e]], 1);
  else
    atomicAdd(&cnt1[ei1[N_EDGES + e]], 1);
}

// fused decoupled-lookback scan. Grid (79,2), all blocks co-resident.
__global__ __launch_bounds__(256) void k_scan(
    int* __restrict__ fill0, int* __restrict__ fill1,
    int* __restrict__ rp0, int* __restrict__ rp1,
    int* __restrict__ aggs) {
  int chunk = blockIdx.x, set = blockIdx.y;
  int* fill = set ? fill1 : fill0;
  int* rp = set ? rp1 : rp0;
  int t = threadIdx.x, lane = t & 63, wv = t >> 6;
  int i = chunk * 256 + t;
  int v = (i < N_NODES) ? fill[i] : 0;
  int s = v;
#pragma unroll
  for (int d = 1; d < 64; d <<= 1) {
    int o = __shfl_up(s, d);
    if (lane >= d) s += o;
  }
  __shared__ int wsum[4];
  if (lane == 63) wsum[wv] = s;
  __syncthreads();
  int pre = 0;
#pragma unroll
  for (int j = 0; j < 4; ++j)
    if (j < wv) pre += wsum[j];
  s += pre;
  int agg = wsum[0] + wsum[1] + wsum[2] + wsum[3];
  if (t == 0)
    __hip_atomic_store(&aggs[set * 128 + chunk], agg | FLAGBIT,
                       __ATOMIC_RELEASE, __HIP_MEMORY_SCOPE_AGENT);
  __shared__ int reds[256];
  int part = 0;
  for (int j = t; j < chunk; j += 256) {
    int a;
    do {
      a = __hip_atomic_load(&aggs[set * 128 + j], __ATOMIC_ACQUIRE,
                            __HIP_MEMORY_SCOPE_AGENT);
    } while (!(a & FLAGBIT));
    part += a & (FLAGBIT - 1);
  }
  reds[t] = part;
  __syncthreads();
  for (int st = 128; st > 0; st >>= 1) {
    if (t < st) reds[t] += reds[t + st];
    __syncthreads();
  }
  int carry = reds[0];
  int excl = carry + s - v;
  if (i < N_NODES) {
    rp[i] = excl;
    fill[i] = excl;
    if (i == N_NODES - 1) rp[N_NODES] = excl + v;
  }
}

__global__ void k_scatter(const int* __restrict__ ei0, const int* __restrict__ ei1,
                          int* __restrict__ fill0, int* __restrict__ fill1,
                          unsigned short* __restrict__ srcs0,
                          unsigned short* __restrict__ srcs1) {
  int e = blockIdx.x * blockDim.x + threadIdx.x;
  if (e >= N_EDGES) return;
  const int* ei = blockIdx.y ? ei1 : ei0;
  int* fill = blockIdx.y ? fill1 : fill0;
  unsigned short* srcs = blockIdx.y ? srcs1 : srcs0;
  int d = ei[N_EDGES + e];
  int pos = atomicAdd(&fill[d], 1);
  srcs[pos] = (unsigned short)ei[e];
}

// ---------------------------------------------------------------------------
// k_gat: ONE WAVE PER (node, set), 32-edge batches aggregated via MFMA:
//   C[head][ch] += A[head][edge] @ B[edge][ch]  (mfma_f32_16x16x32_bf16 x2)
// Lane (eid=lane&15, slot=lane>>4) handles edges 2*eid, 2*eid+1: loads 2 u16
// srcs, 2 float4 asrc, 2 b128 bf16 x rows; 8 exps -> packed-bf16 transposed
// stores into ext[head][edge] and xt[ch-half][ch][edge] (stride 40 for b128
// alignment). B's ch20 column is all-ones => C1 col 4 = softmax denominator.
// After the loop: 4 shfls fetch denom, normalize, b64 bf16 stores to
// xagg [N][2][20][16] (= k_mlp's 640-K A layout).
// ---------------------------------------------------------------------------
__global__ __launch_bounds__(256) void k_gat(
    const unsigned short* __restrict__ xpadbf,
    const float* __restrict__ asrc0, const float* __restrict__ adst0,
    const float* __restrict__ asrc1, const float* __restrict__ adst1,
    const int* __restrict__ rp0, const unsigned short* __restrict__ srcs0,
    const int* __restrict__ rp1, const unsigned short* __restrict__ srcs1,
    unsigned short* __restrict__ xagg) {
  __shared__ unsigned short exsh[4][16][40];
  __shared__ unsigned short xtsh[4][2][16][40];
  int w4 = threadIdx.x >> 6, lane = threadIdx.x & 63;
  int n = blockIdx.x * 2 + (w4 >> 1);
  int g = w4 & 1;
  int eid = lane & 15, slot = lane >> 4;
  unsigned short (*ext)[40] = exsh[w4];
  unsigned short (*xtw)[16][40] = xtsh[w4];
  const float* asrc = g ? asrc1 : asrc0;
  const float* adst = g ? adst1 : adst0;
  const int* rp = g ? rp1 : rp0;
  const unsigned short* srcs = g ? srcs1 : srcs0;
  int k0 = rp[n], k1 = rp[n + 1];
  const float4 adn4 = *(const float4*)&adst[n * 16 + slot * 4];
  f32x4 acc0 = {0.f, 0.f, 0.f, 0.f}, acc1 = acc0;
  int h16 = lane & 15, e8 = (lane >> 4) * 8;
  for (int base = k0; base < k1; base += 32) {
    int e0 = base + 2 * eid, e1 = e0 + 1;
    int sa = (int)srcs[min(e0, k1 - 1)];
    int sbb = (int)srcs[min(e1, k1 - 1)];
    const float4 ava = *(const float4*)&asrc[sa * 16 + slot * 4];
    const float4 avb = *(const float4*)&asrc[sbb * 16 + slot * 4];
    const uint4 xra = *(const uint4*)&xpadbf[(size_t)sa * 32 + slot * 8];
    const uint4 xrb = *(const uint4*)&xpadbf[(size_t)sbb * 32 + slot * 8];
    float ea[4], eb[4];
    {
      float a;
      bool v0 = e0 < k1, v1 = e1 < k1;
      a = ava.x + adn4.x; a = a >= 0.f ? a : NEG * a; ea[0] = v0 ? __expf(a) : 0.f;
      a = ava.y + adn4.y; a = a >= 0.f ? a : NEG * a; ea[1] = v0 ? __expf(a) : 0.f;
      a = ava.z + adn4.z; a = a >= 0.f ? a : NEG * a; ea[2] = v0 ? __expf(a) : 0.f;
      a = ava.w + adn4.w; a = a >= 0.f ? a : NEG * a; ea[3] = v0 ? __expf(a) : 0.f;
      a = avb.x + adn4.x; a = a >= 0.f ? a : NEG * a; eb[0] = v1 ? __expf(a) : 0.f;
      a = avb.y + adn4.y; a = a >= 0.f ? a : NEG * a; eb[1] = v1 ? __expf(a) : 0.f;
      a = avb.z + adn4.z; a = a >= 0.f ? a : NEG * a; eb[2] = v1 ? __expf(a) : 0.f;
      a = avb.w + adn4.w; a = a >= 0.f ? a : NEG * a; eb[3] = v1 ? __expf(a) : 0.f;
    }
#pragma unroll
    for (int r = 0; r < 4; ++r)
      *(unsigned int*)&ext[slot * 4 + r][2 * eid] = pk2bf(ea[r], eb[r]);
    unsigned int ua[4] = {xra.x, xra.y, xra.z, xra.w};
    unsigned int ub[4] = {xrb.x, xrb.y, xrb.z, xrb.w};
#pragma unroll
    for (int q = 0; q < 8; ++q) {
      unsigned int baq = (q & 1) ? (ua[q >> 1] >> 16) : (ua[q >> 1] & 0xffffu);
      unsigned int bbq = (q & 1) ? (ub[q >> 1] >> 16) : (ub[q >> 1] & 0xffffu);
      int ch = slot * 8 + q;
      *(unsigned int*)&xtw[ch >> 4][ch & 15][2 * eid] = baq | (bbq << 16);
    }
    bf16x8 A = *(const bf16x8*)&ext[h16][e8];
    bf16x8 B0 = *(const bf16x8*)&xtw[0][h16][e8];
    bf16x8 B1 = *(const bf16x8*)&xtw[1][h16][e8];
    acc0 = __builtin_amdgcn_mfma_f32_16x16x32_bf16(A, B0, acc0, 0, 0, 0);
    acc1 = __builtin_amdgcn_mfma_f32_16x16x32_bf16(A, B1, acc1, 0, 0, 0);
  }
  // denom[row r] = C1[row][col 4] (ones column at ch20)
  float inv[4];
#pragma unroll
  for (int r = 0; r < 4; ++r) {
    float dr = __shfl(acc1[r], (lane & 48) | 4);
    inv[r] = dr > 0.f ? 1.f / dr : 0.f;
  }
  int s = lane >> 4, c = lane & 15;
  size_t nb = (size_t)n * 640 + g * 320;
  uint2 o0;
  o0.x = pk2bf(acc0[0] * inv[0], acc0[1] * inv[1]);
  o0.y = pk2bf(acc0[2] * inv[2], acc0[3] * inv[3]);
  *(uint2*)&xagg[nb + c * 16 + s * 4] = o0;
  if (c < 4) {
    uint2 o1;
    o1.x = pk2bf(acc1[0] * inv[0], acc1[1] * inv[1]);
    o1.y = pk2bf(acc1[2] * inv[2], acc1[3] * inv[3]);
    *(uint2*)&xagg[nb + 256 + c * 16 + s * 4] = o1;
  }
}

// ---------------------------------------------------------------------------
// k_mlp: 16 nodes/block (1250 blocks). Wave w computes one col-tile of
// layer 1 via 20-step bf16 MFMA (K=640); layers 2-4 (node,col); pool.
// ---------------------------------------------------------------------------
__global__ __launch_bounds__(256) void k_mlp(
    const unsigned short* __restrict__ xagg, const unsigned short* __restrict__ wbigfrag,
    const float* __restrict__ bfold,
    const float* __restrict__ W1m, const float* __restrict__ b1v,
    const float* __restrict__ W2m, const float* __restrict__ b2v,
    const float* __restrict__ W3m, const float* __restrict__ b3v,
    const int* __restrict__ batch,
    float* __restrict__ gsum, int* __restrict__ gcnt) {
  int t = threadIdx.x, w = t >> 6, lane = t & 63;
  int n0 = blockIdx.x * 16;
  __shared__ float o1[16][68];
  __shared__ float o2[16][36];
  __shared__ float o3[16][20];
  __shared__ float o4[16][17];
  __shared__ int bs[16];
  if (t < 16) bs[t] = batch[n0 + t];

  {
    int m = lane & 15, kb = lane >> 4;
    const unsigned short* aptr = xagg + (size_t)(n0 + m) * 640 + kb * 8;
    const unsigned short* bbase = wbigfrag + (size_t)w * 10240 + lane * 8;
    f32x4 acc = {0.f, 0.f, 0.f, 0.f};
#pragma unroll 5
    for (int ks = 0; ks < 20; ++ks) {
      bf16x8 af = *(const bf16x8*)(aptr + ks * 32);
      bf16x8 bfr = *(const bf16x8*)(bbase + (size_t)ks * 512);
      acc = __builtin_amdgcn_mfma_f32_16x16x32_bf16(af, bfr, acc, 0, 0, 0);
    }
    int col = lane & 15, rg = lane >> 4;
#pragma unroll
    for (int r = 0; r < 4; ++r) {
      int row = rg * 4 + r;
      o1[row][w * 16 + col] = fmaxf(acc[r] + bfold[w * 16 + col], 0.f);
    }
  }
  __syncthreads();
  int nd = t >> 4, js = t & 15;
  {
    float a0 = b1v[js], a1 = b1v[js + 16];
#pragma unroll 8
    for (int k = 0; k < 64; ++k) {
      float hv = o1[nd][k];
      a0 = fmaf(hv, W1m[k * 32 + js], a0);
      a1 = fmaf(hv, W1m[k * 32 + js + 16], a1);
    }
    o2[nd][js] = fmaxf(a0, 0.f);
    o2[nd][js + 16] = fmaxf(a1, 0.f);
  }
  __syncthreads();
  {
    float a = b2v[js];
#pragma unroll
    for (int k = 0; k < 32; ++k) a = fmaf(o2[nd][k], W2m[k * 16 + js], a);
    o3[nd][js] = fmaxf(a, 0.f);
  }
  __syncthreads();
  {
    float a = b3v[js];
#pragma unroll
    for (int k = 0; k < 16; ++k) a = fmaf(o3[nd][k], W3m[k * 16 + js], a);
    o4[nd][js] = fmaxf(a, 0.f);
  }
  __syncthreads();
  if (t < 128) {
    int s = t >> 4, jx = t & 15;
    int b = bs[0] + s;
    if (b <= bs[15]) {
      float sum = 0.f; int c = 0;
#pragma unroll
      for (int ndd = 0; ndd < 16; ++ndd)
        if (bs[ndd] == b) { sum += o4[ndd][jx]; ++c; }
      if (c > 0) {
        atomicAdd(&gsum[b * 16 + jx], sum);
        if (jx == 0) atomicAdd(&gcnt[b], c);
      }
    }
  }
}

__global__ void k_head(const float* __restrict__ gsum, const int* __restrict__ gcnt,
                       const float* __restrict__ Wce, const float* __restrict__ bce,
                       const float* __restrict__ Wcv, const float* __restrict__ bcv,
                       float* __restrict__ out) {
  int t = threadIdx.x;
  if (t >= 384) return;
  int half = t / 192, idx = t % 192;
  int b = idx / 3, r = idx % 3;
  float cnt = (float)gcnt[b];
  float inv = cnt > 0.f ? 1.f / cnt : 1.f;
  const float* Wc = half ? Wcv : Wce;
  const float* bc = half ? bcv : bce;
  float v = bc[r];
#pragma unroll
  for (int j = 0; j < 16; ++j) v = fmaf(gsum[b * 16 + j] * inv, Wc[j * 3 + r], v);
  out[t] = v;
}

extern "C" void kernel_launch(void* const* d_in, const int* in_sizes, int n_in,
                              void* d_out, int out_size, void* d_ws, size_t ws_size,
                              hipStream_t stream) {
  const float* x = (const float*)d_in[0];
  const int* ei_i = (const int*)d_in[1];
  const int* ei_t = (const int*)d_in[3];
  const int* batch = (const int*)d_in[5];
  const float* W_i = (const float*)d_in[6];
  const float* as_i = (const float*)d_in[7];
  const float* ad_i = (const float*)d_in[8];
  const float* b_i = (const float*)d_in[9];
  const float* W_t = (const float*)d_in[10];
  const float* as_t = (const float*)d_in[11];
  const float* ad_t = (const float*)d_in[12];
  const float* b_t = (const float*)d_in[13];
  const float* Wf = (const float*)d_in[14];
  const float* bf = (const float*)d_in[15];
  const float* W1 = (const float*)d_in[16];
  const float* b1 = (const float*)d_in[17];
  const float* W2 = (const float*)d_in[18];
  const float* b2 = (const float*)d_in[19];
  const float* W3 = (const float*)d_in[20];
  const float* b3 = (const float*)d_in[21];
  const float* Wce = (const float*)d_in[22];
  const float* bce = (const float*)d_in[23];
  const float* Wcv = (const float*)d_in[24];
  const float* bcv = (const float*)d_in[25];

  char* ws = (char*)d_ws;
  size_t off = 0;
  auto take = [&](size_t bytes) {
    void* p = ws + off;
    off = (off + bytes + 255) & ~(size_t)255;
    return p;
  };
  unsigned short* xpadbf = (unsigned short*)take((size_t)N_NODES * 32 * 2);
  unsigned short* xagg = (unsigned short*)take((size_t)N_NODES * 640 * 2);
  float* wsall = (float*)take((size_t)1280 * 4);
  unsigned short* wbigfrag = (unsigned short*)take((size_t)40960 * 2);
  float* bfold = (float*)take((size_t)64 * 4);
  float* asrc_i = (float*)take((size_t)N_NODES * 16 * 4);
  float* adst_i = (float*)take((size_t)N_NODES * 16 * 4);
  float* asrc_t = (float*)take((size_t)N_NODES * 16 * 4);
  float* adst_t = (float*)take((size_t)N_NODES * 16 * 4);
  int* rowptr_i = (int*)take((size_t)(N_NODES + 1) * 4);
  int* rowptr_t = (int*)take((size_t)(N_NODES + 1) * 4);
  int* fill_i = (int*)take((size_t)N_NODES * 4);
  int* fill_t = (int*)take((size_t)N_NODES * 4);
  int* csums = (int*)take((size_t)2 * 128 * 4);
  unsigned short* srcs_i = (unsigned short*)take((size_t)N_EDGES * 2);
  unsigned short* srcs_t = (unsigned short*)take((size_t)N_EDGES * 2);
  float* gsum = (float*)take((size_t)NG * 16 * 4);
  int* gcnt = (int*)take((size_t)NG * 4);

  int prep_items = 1280 + 40960 + 256 + N_NODES + N_NODES + NG * 16 + NG + 256;
  k_prep<<<(prep_items + 255) / 256, 256, 0, stream>>>(
      W_i, as_i, ad_i, W_t, as_t, ad_t, Wf, bf, b_i, b_t,
      wsall, wbigfrag, bfold, fill_i, fill_t, gsum, gcnt, csums);

  k_alpha<<<N_NODES / 16, 256, 0, stream>>>(x, wsall, xpadbf,
                                            asrc_i, adst_i, asrc_t, adst_t);

  dim3 egrid((N_EDGES + 255) / 256, 2);
  k_hist<<<egrid, 256, 0, stream>>>(ei_i, ei_t, fill_i, fill_t);
  dim3 sgrid(NCHUNK, 2);
  k_scan<<<sgrid, 256, 0, stream>>>(fill_i, fill_t, rowptr_i, rowptr_t, csums);
  k_scatter<<<egrid, 256, 0, stream>>>(ei_i, ei_t, fill_i, fill_t, srcs_i, srcs_t);

  k_gat<<<N_NODES / 2, 256, 0, stream>>>(xpadbf, asrc_i, adst_i, asrc_t, adst_t,
                                         rowptr_i, srcs_i, rowptr_t, srcs_t,
                                         xagg);

  k_mlp<<<N_NODES / 16, 256, 0, stream>>>(xagg, wbigfrag, bfold,
                                          W1, b1, W2, b2, W3, b3,
                                          batch, gsum, gcnt);

  k_head<<<1, 384, 0, stream>>>(gsum, gcnt, Wce, bce, Wcv, bcv, (float*)d_out);
}